// Round 19
// baseline (179.293 us; speedup 1.0000x reference)
//
#include <hip/hip_runtime.h>
#include <hip/hip_bf16.h>

#define BATCH 2
#define SEQ   2048
#define DIM   1024
#define HEADS 16
#define DIMH  64
#define BK    32
#define LOG2E 1.44269504088896340736f
#define SM_SHIFT 16.0f   // fixed softmax shift (log2 domain); |st| <= ~12

typedef __attribute__((ext_vector_type(8))) short short8;
typedef __attribute__((ext_vector_type(4))) short short4v;
typedef __attribute__((ext_vector_type(4))) float floatx4;

static __device__ __forceinline__ void gload_lds16(const void* g, void* l) {
    __builtin_amdgcn_global_load_lds(
        (const __attribute__((address_space(1))) void*)g,
        (__attribute__((address_space(3))) void*)l, 16, 0, 0);
}

// truncation pack: bf16(a) | bf16(b)<<16 (scale-invariant err cancels in P*V/sum)
static __device__ __forceinline__ unsigned pk_trunc(float a, float b) {
    return (__float_as_uint(b) & 0xffff0000u) | (__float_as_uint(a) >> 16);
}

// ---------------------------------------------------------------------------
// One conversion pass: x,Wq,Wk,Wv -> d_out scratch [0,4M | 4M..7M); Wo -> dwo.
// ---------------------------------------------------------------------------
__global__ __launch_bounds__(256) void conv_all(
    const float* __restrict__ x,  const float* __restrict__ Wq,
    const float* __restrict__ Wk, const float* __restrict__ Wv,
    const float* __restrict__ Wo,
    __hip_bfloat16* __restrict__ dst, __hip_bfloat16* __restrict__ dwo)
{
    const size_t NX = (size_t)BATCH * SEQ * DIM;   // 4M
    const size_t NW = (size_t)DIM * DIM;           // 1M
    size_t i = ((size_t)blockIdx.x * 256 + threadIdx.x) * 4;
    if (i >= NX + 4 * NW) return;
    const float* src; __hip_bfloat16* d;
    if (i < NX) { src = x + i; d = dst + i; }
    else if (i < NX + 3 * NW) {
        size_t j = i - NX;
        int w = (int)(j >> 20);
        src = ((w == 0) ? Wq : (w == 1) ? Wk : Wv) + (j & (NW - 1));
        d = dst + i;
    } else {
        size_t off = i - (NX + 3 * NW);
        src = Wo + off; d = dwo + off;
    }
    floatx4 f = *reinterpret_cast<const floatx4*>(src);
    short4v o;
    #pragma unroll
    for (int e = 0; e < 4; ++e) {
        __hip_bfloat16 t = __float2bfloat16(f[e]);
        o[e] = *reinterpret_cast<short*>(&t);
    }
    *reinterpret_cast<short4v*>(d) = o;
}

// ---------------------------------------------------------------------------
// Merged QKV GEMM — r18-VERIFIED (45.1us): 128x128 dbuf + T4 counted vmcnt.
// Stage = 4 global_load_lds/thread; two stages in flight; vmcnt(4) waits
// only the oldest 4 (buf cur), t+1 stage rides through the barrier.
// z = n0>>10: z==0 Q (pre-scaled 0.125*log2e, head-split); z==1 K
// head-split; z==2 V transposed [b,h,dv,n].
// ---------------------------------------------------------------------------
__global__ __launch_bounds__(256) void gemm_qkv(
    const __hip_bfloat16* __restrict__ xbf,
    const __hip_bfloat16* __restrict__ wbf,
    __hip_bfloat16* __restrict__ qkv)
{
    __shared__ __align__(16) short As[2][128 * BK];   // 2 x 8KB
    __shared__ __align__(16) short Bs[2][128 * BK];   // 2 x 8KB

    const int tid  = threadIdx.x;
    const int wv   = tid >> 6;
    const int lane = tid & 63;
    const int quad = lane >> 4;
    const int l16  = lane & 15;
    const int wm   = wv >> 1, wn = wv & 1;
    const int m0   = blockIdx.x * 128;
    const int n0   = blockIdx.y * 128;
    const int z    = n0 >> 10;
    __hip_bfloat16* out = qkv + (size_t)z * (BATCH * SEQ * DIM);

    const int srow = tid >> 2;
    const int scol = (tid & 3) * 8;

    floatx4 acc[4][4] = {};

#define QSTAGE(buf, k0v) do {                                                       \
    _Pragma("unroll")                                                               \
    for (int i_ = 0; i_ < 2; ++i_) {                                                \
        gload_lds16(xbf + (size_t)(m0 + srow + i_ * 64) * DIM + (k0v) + scol,       \
                    (char*)As[buf] + i_ * 4096 + wv * 1024);                        \
        gload_lds16(wbf + (size_t)(n0 + srow + i_ * 64) * DIM + (k0v) + scol,       \
                    (char*)Bs[buf] + i_ * 4096 + wv * 1024);                        \
    } } while (0)

    QSTAGE(0, 0);                        // 4 loads in flight

    int cur = 0;
    for (int t = 0; t < DIM / BK; ++t) {
        if (t + 1 < DIM / BK) {
            QSTAGE(cur ^ 1, (t + 1) * BK);                    // 8 in flight
            asm volatile("s_waitcnt vmcnt(4)" ::: "memory");  // oldest 4 = buf cur
        } else {
            asm volatile("s_waitcnt vmcnt(0)" ::: "memory");  // epilogue drain
        }
        __builtin_amdgcn_s_barrier();    // all waves: buf cur fully written
        __builtin_amdgcn_sched_barrier(0);

        short8 af[4], bf[4];
        #pragma unroll
        for (int mt = 0; mt < 4; ++mt)
            af[mt] = *reinterpret_cast<const short8*>(
                &As[cur][(wm * 64 + mt * 16 + l16) * 32 + quad * 8]);
        #pragma unroll
        for (int nt = 0; nt < 4; ++nt)
            bf[nt] = *reinterpret_cast<const short8*>(
                &Bs[cur][(wn * 64 + nt * 16 + l16) * 32 + quad * 8]);
        #pragma unroll
        for (int mt = 0; mt < 4; ++mt)
            #pragma unroll
            for (int nt = 0; nt < 4; ++nt)
                acc[mt][nt] = __builtin_amdgcn_mfma_f32_16x16x32_bf16(
                    af[mt], bf[nt], acc[mt][nt], 0, 0, 0);

        __builtin_amdgcn_s_barrier();    // reads of buf cur done before overwrite
        cur ^= 1;
    }
#undef QSTAGE

    const float esc = (z == 0) ? (0.125f * LOG2E) : 1.0f;
    #pragma unroll
    for (int mt = 0; mt < 4; ++mt) {
        #pragma unroll
        for (int nt = 0; nt < 4; ++nt) {
            const int n  = n0 + wn * 64 + nt * 16 + l16;
            const int hh = (n >> 6) & 15, dv = n & 63;
            #pragma unroll
            for (int r = 0; r < 4; ++r) {
                const int m  = m0 + wm * 64 + mt * 16 + quad * 4 + r;
                const int bb = m >> 11, nn = m & (SEQ - 1);
                const float v = acc[mt][nt][r] * esc;
                if (z < 2)
                    out[((size_t)(bb * HEADS + hh) * SEQ + nn) * DIMH + dv] = __float2bfloat16(v);
                else
                    out[((size_t)(bb * HEADS + hh) * DIMH + dv) * SEQ + nn] = __float2bfloat16(v);
            }
        }
    }
}

// ---------------------------------------------------------------------------
// Output projection, 64x128 tiles (r10-verified: grid 512 = 2 blocks/CU)
// + T4 counted vmcnt (r18-verified pattern from gemm_qkv): stage = 3
// global_load_lds/thread (1 A + 2 B); two stages in flight (6); vmcnt(3)
// waits only the oldest 3 (buf cur).  Same barrier-pair ordering.
// A gathered from head-split Q region; k-step within one head.
// ---------------------------------------------------------------------------
__global__ __launch_bounds__(256) void gemm_out(
    const __hip_bfloat16* __restrict__ qhs,
    const __hip_bfloat16* __restrict__ W,
    float* __restrict__ C)
{
    __shared__ __align__(16) short As[2][64 * BK];    // 2 x 4KB
    __shared__ __align__(16) short Bs[2][128 * BK];   // 2 x 8KB

    const int tid  = threadIdx.x;
    const int wv   = tid >> 6;
    const int lane = tid & 63;
    const int quad = lane >> 4;
    const int l16  = lane & 15;
    const int wn   = wv;                 // N-strip of 32 per wave
    const int m0   = blockIdx.x * 64;
    const int n0   = blockIdx.y * 128;

    const int srow = tid >> 2;           // 0..63
    const int scol = (tid & 3) * 8;

    floatx4 acc[4][2] = {};

#define OSTAGE(buf, k0v) do {                                                       \
    const int h_    = (k0v) >> 6;                                                   \
    const int koff_ = (k0v) & 63;                                                   \
    const int mA_   = m0 + srow;                                                    \
    const int bbA_  = mA_ >> 11, nnA_ = mA_ & (SEQ - 1);                            \
    gload_lds16(qhs + ((size_t)(bbA_ * HEADS + h_) * SEQ + nnA_) * DIMH + koff_ + scol, \
                (char*)As[buf] + wv * 1024);                                        \
    _Pragma("unroll")                                                               \
    for (int i_ = 0; i_ < 2; ++i_)                                                  \
        gload_lds16(W + (size_t)(n0 + srow + i_ * 64) * DIM + (k0v) + scol,         \
                    (char*)Bs[buf] + i_ * 4096 + wv * 1024);                        \
    } while (0)

    OSTAGE(0, 0);                        // 3 loads in flight

    int cur = 0;
    for (int t = 0; t < DIM / BK; ++t) {
        if (t + 1 < DIM / BK) {
            OSTAGE(cur ^ 1, (t + 1) * BK);                    // 6 in flight
            asm volatile("s_waitcnt vmcnt(3)" ::: "memory");  // oldest 3 = buf cur
        } else {
            asm volatile("s_waitcnt vmcnt(0)" ::: "memory");  // epilogue drain
        }
        __builtin_amdgcn_s_barrier();    // all waves: buf cur fully written
        __builtin_amdgcn_sched_barrier(0);

        short8 af[4], bf[2];
        #pragma unroll
        for (int mt = 0; mt < 4; ++mt)
            af[mt] = *reinterpret_cast<const short8*>(
                &As[cur][(mt * 16 + l16) * 32 + quad * 8]);
        #pragma unroll
        for (int nt = 0; nt < 2; ++nt)
            bf[nt] = *reinterpret_cast<const short8*>(
                &Bs[cur][(wn * 32 + nt * 16 + l16) * 32 + quad * 8]);
        #pragma unroll
        for (int mt = 0; mt < 4; ++mt)
            #pragma unroll
            for (int nt = 0; nt < 2; ++nt)
                acc[mt][nt] = __builtin_amdgcn_mfma_f32_16x16x32_bf16(
                    af[mt], bf[nt], acc[mt][nt], 0, 0, 0);

        __builtin_amdgcn_s_barrier();    // reads of buf cur done before overwrite
        cur ^= 1;
    }
#undef OSTAGE

    #pragma unroll
    for (int mt = 0; mt < 4; ++mt)
        #pragma unroll
        for (int nt = 0; nt < 2; ++nt) {
            const int n = n0 + wn * 32 + nt * 16 + l16;
            #pragma unroll
            for (int r = 0; r < 4; ++r) {
                const int m = m0 + mt * 16 + quad * 4 + r;
                C[(size_t)m * DIM + n] = acc[mt][nt][r];
            }
        }
}

// ---------------------------------------------------------------------------
// Causal flash attention, UNPAIRED-LPT (r13-verified): 1024 blocks, ONE
// 64-row tile each, heavy tiles first.  3 blocks/CU resident.  Monotone j
// staging pointers; diagonal mask only at s == total-1; epilogue hoisted.
// Double-Q per wave + K/V LDS dbuf, single barrier per step.
// O written in-place over Q (block-private rows).
// ---------------------------------------------------------------------------
__global__ __launch_bounds__(256) void attn_causal(
    __hip_bfloat16* __restrict__ qkv)
{
    __shared__ __align__(16) short kt[2][64 * 64];     // [slot][j][k], swizzled
    __shared__ __align__(16) short vt[2][64 * 64];     // [slot][dv][j], swizzled
    __shared__ __align__(16) short pt[2][2][16 * 72];  // [g][sub] P^T [q][j]

    const int id    = blockIdx.x;        // 0..1023
    const int combo = id & 31;           // (h,b): combo%8 pins XCD class
    const int b     = combo >> 4;
    const int h     = combo & 15;
    const int tile  = 31 - (id >> 5);    // LPT: heaviest (32 steps) first
    const int total = tile + 1;

    const size_t hoff = (size_t)(b * HEADS + h) * SEQ * DIMH;
    const size_t one  = (size_t)BATCH * SEQ * DIM;
    __hip_bfloat16* qb        = qkv + hoff;             // Q in, O out (in-place)
    const __hip_bfloat16* kb  = qkv + one + hoff;       // [n][dv]
    const __hip_bfloat16* vtg = qkv + 2 * one + hoff;   // [dv][n]

    const int tid  = threadIdx.x;
    const int wv   = tid >> 6;
    const int g    = wv >> 1;            // wave-pair (0,1)
    const int jh   = wv & 1;             // j-half owner
    const int lane = tid & 63;
    const int quad = lane >> 4;
    const int l16  = lane & 15;
    const int xr   = l16 & 7;

    const int crow = tid >> 3;           // staging row 0..31 (x2)
    const int cjc  = tid & 7;
    const int coff = ((cjc ^ (crow & 7)) * 8);

    const short8 kone8 = {0x3F80, 0x3F80, 0x3F80, 0x3F80,
                          0x3F80, 0x3F80, 0x3F80, 0x3F80};

    const int qbase = tile * 64 + g * 16;   // sub sb: rows qbase + sb*32 .. +15
    short8 aq[2][2];                     // [sub][half]
    #pragma unroll
    for (int sb = 0; sb < 2; ++sb) {
        aq[sb][0] = *reinterpret_cast<const short8*>(
            qb + (size_t)(qbase + sb * 32 + l16) * DIMH + quad * 8);
        aq[sb][1] = *reinterpret_cast<const short8*>(
            qb + (size_t)(qbase + sb * 32 + l16) * DIMH + 32 + quad * 8);
    }
    floatx4 oacc[2][4] = {};             // [sub][dt]
    floatx4 lsum[2] = {};

    // incrementing staging pointers (j advances 0,64,128,... monotonically)
    const __hip_bfloat16* kp0 = kb + (size_t)crow * DIMH + cjc * 8;
    const __hip_bfloat16* kp1 = kb + (size_t)(crow + 32) * DIMH + cjc * 8;
    const __hip_bfloat16* vp0 = vtg + (size_t)crow * SEQ + cjc * 8;
    const __hip_bfloat16* vp1 = vtg + (size_t)(crow + 32) * SEQ + cjc * 8;

    short8 kreg[2], vreg[2];
    kreg[0] = *reinterpret_cast<const short8*>(kp0);
    kreg[1] = *reinterpret_cast<const short8*>(kp1);
    vreg[0] = *reinterpret_cast<const short8*>(vp0);
    vreg[1] = *reinterpret_cast<const short8*>(vp1);
    kp0 += 64 * DIMH; kp1 += 64 * DIMH; vp0 += 64; vp1 += 64;

    *reinterpret_cast<short8*>(&kt[0][crow * 64 + coff])        = kreg[0];
    *reinterpret_cast<short8*>(&kt[0][(crow + 32) * 64 + coff]) = kreg[1];
    *reinterpret_cast<short8*>(&vt[0][crow * 64 + coff])        = vreg[0];
    *reinterpret_cast<short8*>(&vt[0][(crow + 32) * 64 + coff]) = vreg[1];
    __syncthreads();

    int cur = 0;
    for (int s = 0; s < total; ++s) {
        const int j0 = s * 64;
        const bool hasn = (s + 1 < total);

        if (hasn) {                      // issue next step's K/V loads early
            kreg[0] = *reinterpret_cast<const short8*>(kp0);
            kreg[1] = *reinterpret_cast<const short8*>(kp1);
            vreg[0] = *reinterpret_cast<const short8*>(vp0);
            vreg[1] = *reinterpret_cast<const short8*>(vp1);
            kp0 += 64 * DIMH; kp1 += 64 * DIMH; vp0 += 64; vp1 += 64;
        }

        // St[j][q] = K Q^T: read K fragments ONCE, use for both subs
        floatx4 st[2][2];                // [sub][tt]
        #pragma unroll
        for (int tt = 0; tt < 2; ++tt) {
            const int rw = (jh * 2 + tt) * 16 + l16;
            short8 a0 = *reinterpret_cast<const short8*>(&kt[cur][rw * 64 + (quad ^ xr) * 8]);
            short8 a1 = *reinterpret_cast<const short8*>(&kt[cur][rw * 64 + ((quad + 4) ^ xr) * 8]);
            #pragma unroll
            for (int sb = 0; sb < 2; ++sb) {
                floatx4 zz = {};
                zz         = __builtin_amdgcn_mfma_f32_16x16x32_bf16(a0, aq[sb][0], zz, 0, 0, 0);
                st[sb][tt] = __builtin_amdgcn_mfma_f32_16x16x32_bf16(a1, aq[sb][1], zz, 0, 0, 0);
            }
        }

        if (s == total - 1) {            // only the final step touches the diagonal
            #pragma unroll
            for (int sb = 0; sb < 2; ++sb) {
                const int qg = qbase + sb * 32 + l16;
                #pragma unroll
                for (int tt = 0; tt < 2; ++tt)
                    #pragma unroll
                    for (int r = 0; r < 4; ++r) {
                        const int jg = j0 + (jh * 2 + tt) * 16 + quad * 4 + r;
                        if (jg > qg) st[sb][tt][r] = -3.0e38f;
                    }
            }
        }

        #pragma unroll
        for (int sb = 0; sb < 2; ++sb)
            #pragma unroll
            for (int tt = 0; tt < 2; ++tt)
                #pragma unroll
                for (int r = 0; r < 4; ++r)
                    st[sb][tt][r] = __builtin_amdgcn_exp2f(st[sb][tt][r] - SM_SHIFT);

        // P^T pack per sub (wave-disjoint pt regions)
        short8 ph[2];
        #pragma unroll
        for (int sb = 0; sb < 2; ++sb) {
            #pragma unroll
            for (int tt = 0; tt < 2; ++tt) {
                const int t = jh * 2 + tt;
                *reinterpret_cast<unsigned*>(&pt[g][sb][l16 * 72 + t * 16 + quad * 4]) =
                    pk_trunc(st[sb][tt][0], st[sb][tt][1]);
                *reinterpret_cast<unsigned*>(&pt[g][sb][l16 * 72 + t * 16 + quad * 4 + 2]) =
                    pk_trunc(st[sb][tt][2], st[sb][tt][3]);
            }
            ph[sb] = *reinterpret_cast<const short8*>(&pt[g][sb][l16 * 72 + jh * 32 + quad * 8]);
            lsum[sb] = __builtin_amdgcn_mfma_f32_16x16x32_bf16(kone8, ph[sb], lsum[sb], 0, 0, 0);
        }

        // O^T += V^T P^T: read V fragment ONCE, use for both subs
        #pragma unroll
        for (int dt = 0; dt < 4; ++dt) {
            const int rw = dt * 16 + l16;
            short8 vh = *reinterpret_cast<const short8*>(
                &vt[cur][rw * 64 + ((quad + 4 * jh) ^ xr) * 8]);
            #pragma unroll
            for (int sb = 0; sb < 2; ++sb)
                oacc[sb][dt] = __builtin_amdgcn_mfma_f32_16x16x32_bf16(
                    vh, ph[sb], oacc[sb][dt], 0, 0, 0);
        }

        if (hasn) {                      // commit next step's K/V into other slot
            *reinterpret_cast<short8*>(&kt[cur ^ 1][crow * 64 + coff])        = kreg[0];
            *reinterpret_cast<short8*>(&kt[cur ^ 1][(crow + 32) * 64 + coff]) = kreg[1];
            *reinterpret_cast<short8*>(&vt[cur ^ 1][crow * 64 + coff])        = vreg[0];
            *reinterpret_cast<short8*>(&vt[cur ^ 1][(crow + 32) * 64 + coff]) = vreg[1];
        }

        __syncthreads();                 // commits visible; [cur] reads all done
        cur ^= 1;
    }

    // ---- epilogue (outside the loop; kt/vt dead, last barrier already done)
    float* xo = reinterpret_cast<float*>(g == 0 ? kt[0] : vt[0]);  // 2048 floats
    float* xl = reinterpret_cast<float*>(pt);                      // 256 floats
    if (jh == 1) {
        #pragma unroll
        for (int sb = 0; sb < 2; ++sb) {
            #pragma unroll
            for (int dt = 0; dt < 4; ++dt)
                #pragma unroll
                for (int r = 0; r < 4; ++r)
                    xo[sb * 1024 + (dt * 4 + r) * 64 + lane] = oacc[sb][dt][r];
            xl[(g * 2 + sb) * 64 + lane] = lsum[sb][0];
        }
    }
    __syncthreads();
    if (jh == 0) {
        #pragma unroll
        for (int sb = 0; sb < 2; ++sb) {
            const float rl = 1.0f / (lsum[sb][0] + xl[(g * 2 + sb) * 64 + lane]);
            #pragma unroll
            for (int dt = 0; dt < 4; ++dt)
                #pragma unroll
                for (int r = 0; r < 4; ++r) {
                    const float ov = oacc[sb][dt][r] +
                                     xo[sb * 1024 + (dt * 4 + r) * 64 + lane];
                    qb[(size_t)(qbase + sb * 32 + l16) * DIMH + dt * 16 + quad * 4 + r] =
                        __float2bfloat16(ov * rl);
                }
        }
    }
}

// ---------------------------------------------------------------------------

extern "C" void kernel_launch(void* const* d_in, const int* in_sizes, int n_in,
                              void* d_out, int out_size, void* d_ws, size_t ws_size,
                              hipStream_t stream) {
    const float* x  = (const float*)d_in[0];
    const float* Wq = (const float*)d_in[1];
    const float* Wk = (const float*)d_in[2];
    const float* Wv = (const float*)d_in[3];
    const float* Wo = (const float*)d_in[4];

    // ws: qkv bf16 [0,24M) | wobf bf16 [24M,26M)
    __hip_bfloat16* qkv  = (__hip_bfloat16*)d_ws;
    __hip_bfloat16* wobf = (__hip_bfloat16*)((char*)d_ws + (size_t)24 * 1024 * 1024);

    // d_out (16 MB) as bf16 scratch until gemm_out overwrites it
    __hip_bfloat16* xbf = (__hip_bfloat16*)d_out;
    __hip_bfloat16* wbf = xbf + (size_t)BATCH * SEQ * DIM;

    conv_all  <<<8192, 256, 0, stream>>>(x, Wq, Wk, Wv, Wo, xbf, wobf);
    gemm_qkv  <<<dim3((BATCH * SEQ) / 128, (3 * DIM) / 128), 256, 0, stream>>>(xbf, wbf, qkv);
    attn_causal<<<dim3(1024), 256, 0, stream>>>(qkv);
    gemm_out  <<<dim3((BATCH * SEQ) / 64, DIM / 128), 256, 0, stream>>>(qkv, wobf, (float*)d_out);
}

// Round 20
// 176.376 us; speedup vs baseline: 1.0165x; 1.0165x over previous
//
#include <hip/hip_runtime.h>
#include <hip/hip_bf16.h>

#define BATCH 2
#define SEQ   2048
#define DIM   1024
#define HEADS 16
#define DIMH  64
#define BK    32
#define LOG2E 1.44269504088896340736f
#define SM_SHIFT 16.0f   // fixed softmax shift (log2 domain); |st| <= ~12

typedef __attribute__((ext_vector_type(8))) short short8;
typedef __attribute__((ext_vector_type(4))) short short4v;
typedef __attribute__((ext_vector_type(4))) float floatx4;

static __device__ __forceinline__ void gload_lds16(const void* g, void* l) {
    __builtin_amdgcn_global_load_lds(
        (const __attribute__((address_space(1))) void*)g,
        (__attribute__((address_space(3))) void*)l, 16, 0, 0);
}

// truncation pack: bf16(a) | bf16(b)<<16 (scale-invariant err cancels in P*V/sum)
static __device__ __forceinline__ unsigned pk_trunc(float a, float b) {
    return (__float_as_uint(b) & 0xffff0000u) | (__float_as_uint(a) >> 16);
}

// ---------------------------------------------------------------------------
// One conversion pass: x,Wq,Wk,Wv -> d_out scratch [0,4M | 4M..7M); Wo -> dwo.
// ---------------------------------------------------------------------------
__global__ __launch_bounds__(256) void conv_all(
    const float* __restrict__ x,  const float* __restrict__ Wq,
    const float* __restrict__ Wk, const float* __restrict__ Wv,
    const float* __restrict__ Wo,
    __hip_bfloat16* __restrict__ dst, __hip_bfloat16* __restrict__ dwo)
{
    const size_t NX = (size_t)BATCH * SEQ * DIM;   // 4M
    const size_t NW = (size_t)DIM * DIM;           // 1M
    size_t i = ((size_t)blockIdx.x * 256 + threadIdx.x) * 4;
    if (i >= NX + 4 * NW) return;
    const float* src; __hip_bfloat16* d;
    if (i < NX) { src = x + i; d = dst + i; }
    else if (i < NX + 3 * NW) {
        size_t j = i - NX;
        int w = (int)(j >> 20);
        src = ((w == 0) ? Wq : (w == 1) ? Wk : Wv) + (j & (NW - 1));
        d = dst + i;
    } else {
        size_t off = i - (NX + 3 * NW);
        src = Wo + off; d = dwo + off;
    }
    floatx4 f = *reinterpret_cast<const floatx4*>(src);
    short4v o;
    #pragma unroll
    for (int e = 0; e < 4; ++e) {
        __hip_bfloat16 t = __float2bfloat16(f[e]);
        o[e] = *reinterpret_cast<short*>(&t);
    }
    *reinterpret_cast<short4v*>(d) = o;
}

// ---------------------------------------------------------------------------
// Merged QKV GEMM — r18 T4 counted-vmcnt structure extended to PREFETCH
// DEPTH 2 (3-slot LDS rotation, 48KB, still 3 blocks/CU since grid=768):
// prologue stages t=0,1; iter t stages (t+2)%3 then waits vmcnt(8)
// (12 loads in flight -> drain oldest 4 = buf t); tails vmcnt(4)/vmcnt(0).
// Two-barrier ordering identical to r18 (verified): barrier 1 publishes
// buf t after the block-uniform drain; barrier 2 orders all reads of
// buf t before the slot's next overwrite (which happens after it).
// Rationale: FETCH=2x unique -> many stage loads are cold L2 misses
// (~900cy); depth-2 gives 2 iterations of slack instead of 1.
// z = n0>>10: z==0 Q (pre-scaled 0.125*log2e, head-split); z==1 K
// head-split; z==2 V transposed [b,h,dv,n].
// ---------------------------------------------------------------------------
__global__ __launch_bounds__(256) void gemm_qkv(
    const __hip_bfloat16* __restrict__ xbf,
    const __hip_bfloat16* __restrict__ wbf,
    __hip_bfloat16* __restrict__ qkv)
{
    __shared__ __align__(16) short As[3][128 * BK];   // 3 x 8KB
    __shared__ __align__(16) short Bs[3][128 * BK];   // 3 x 8KB

    const int tid  = threadIdx.x;
    const int wv   = tid >> 6;
    const int lane = tid & 63;
    const int quad = lane >> 4;
    const int l16  = lane & 15;
    const int wm   = wv >> 1, wn = wv & 1;
    const int m0   = blockIdx.x * 128;
    const int n0   = blockIdx.y * 128;
    const int z    = n0 >> 10;
    __hip_bfloat16* out = qkv + (size_t)z * (BATCH * SEQ * DIM);

    const int srow = tid >> 2;
    const int scol = (tid & 3) * 8;

    floatx4 acc[4][4] = {};

#define QSTAGE(buf, k0v) do {                                                       \
    _Pragma("unroll")                                                               \
    for (int i_ = 0; i_ < 2; ++i_) {                                                \
        gload_lds16(xbf + (size_t)(m0 + srow + i_ * 64) * DIM + (k0v) + scol,       \
                    (char*)As[buf] + i_ * 4096 + wv * 1024);                        \
        gload_lds16(wbf + (size_t)(n0 + srow + i_ * 64) * DIM + (k0v) + scol,       \
                    (char*)Bs[buf] + i_ * 4096 + wv * 1024);                        \
    } } while (0)

    const int NT = DIM / BK;             // 32
    QSTAGE(0, 0);                        // stage t=0 (4 loads)
    QSTAGE(1, BK);                       // stage t=1 (8 in flight)

    int cur = 0;
    for (int t = 0; t < NT; ++t) {
        if (t + 2 < NT) {
            QSTAGE((cur + 2) % 3, (t + 2) * BK);              // 12 in flight
            asm volatile("s_waitcnt vmcnt(8)" ::: "memory");  // oldest 4 = buf t
        } else if (t + 1 < NT) {
            asm volatile("s_waitcnt vmcnt(4)" ::: "memory");  // leave t+1 in flight
        } else {
            asm volatile("s_waitcnt vmcnt(0)" ::: "memory");  // final drain
        }
        __builtin_amdgcn_s_barrier();    // all waves: buf cur fully written
        __builtin_amdgcn_sched_barrier(0);

        short8 af[4], bf[4];
        #pragma unroll
        for (int mt = 0; mt < 4; ++mt)
            af[mt] = *reinterpret_cast<const short8*>(
                &As[cur][(wm * 64 + mt * 16 + l16) * 32 + quad * 8]);
        #pragma unroll
        for (int nt = 0; nt < 4; ++nt)
            bf[nt] = *reinterpret_cast<const short8*>(
                &Bs[cur][(wn * 64 + nt * 16 + l16) * 32 + quad * 8]);
        #pragma unroll
        for (int mt = 0; mt < 4; ++mt)
            #pragma unroll
            for (int nt = 0; nt < 4; ++nt)
                acc[mt][nt] = __builtin_amdgcn_mfma_f32_16x16x32_bf16(
                    af[mt], bf[nt], acc[mt][nt], 0, 0, 0);

        __builtin_amdgcn_s_barrier();    // reads of buf cur done before overwrite
        cur = (cur + 1) % 3;
    }
#undef QSTAGE

    const float esc = (z == 0) ? (0.125f * LOG2E) : 1.0f;
    #pragma unroll
    for (int mt = 0; mt < 4; ++mt) {
        #pragma unroll
        for (int nt = 0; nt < 4; ++nt) {
            const int n  = n0 + wn * 64 + nt * 16 + l16;
            const int hh = (n >> 6) & 15, dv = n & 63;
            #pragma unroll
            for (int r = 0; r < 4; ++r) {
                const int m  = m0 + wm * 64 + mt * 16 + quad * 4 + r;
                const int bb = m >> 11, nn = m & (SEQ - 1);
                const float v = acc[mt][nt][r] * esc;
                if (z < 2)
                    out[((size_t)(bb * HEADS + hh) * SEQ + nn) * DIMH + dv] = __float2bfloat16(v);
                else
                    out[((size_t)(bb * HEADS + hh) * DIMH + dv) * SEQ + nn] = __float2bfloat16(v);
            }
        }
    }
}

// ---------------------------------------------------------------------------
// Output projection, 64x128 tiles (r10/r18-verified: grid 512 = 2 blocks/CU,
// plain __syncthreads dbuf — r19's T4 here was null: 2-block TLP already
// hides the drain).  4 waves = 4 N-strips of 32; per wave 4x2 fragments.
// A gathered from head-split Q region; k-step within one head.
// ---------------------------------------------------------------------------
__global__ __launch_bounds__(256) void gemm_out(
    const __hip_bfloat16* __restrict__ qhs,
    const __hip_bfloat16* __restrict__ W,
    float* __restrict__ C)
{
    __shared__ __align__(16) short As[2][64 * BK];    // 2 x 4KB
    __shared__ __align__(16) short Bs[2][128 * BK];   // 2 x 8KB

    const int tid  = threadIdx.x;
    const int wv   = tid >> 6;
    const int lane = tid & 63;
    const int quad = lane >> 4;
    const int l16  = lane & 15;
    const int wn   = wv;                 // N-strip of 32 per wave
    const int m0   = blockIdx.x * 64;
    const int n0   = blockIdx.y * 128;

    const int srow = tid >> 2;           // 0..63
    const int scol = (tid & 3) * 8;

    floatx4 acc[4][2] = {};

#define OSTAGE(buf, k0v) do {                                                       \
    const int h_    = (k0v) >> 6;                                                   \
    const int koff_ = (k0v) & 63;                                                   \
    const int mA_   = m0 + srow;                                                    \
    const int bbA_  = mA_ >> 11, nnA_ = mA_ & (SEQ - 1);                            \
    gload_lds16(qhs + ((size_t)(bbA_ * HEADS + h_) * SEQ + nnA_) * DIMH + koff_ + scol, \
                (char*)As[buf] + wv * 1024);                                        \
    _Pragma("unroll")                                                               \
    for (int i_ = 0; i_ < 2; ++i_)                                                  \
        gload_lds16(W + (size_t)(n0 + srow + i_ * 64) * DIM + (k0v) + scol,         \
                    (char*)Bs[buf] + i_ * 4096 + wv * 1024);                        \
    } while (0)

    OSTAGE(0, 0);
    __syncthreads();

    int cur = 0;
    for (int t = 0; t < DIM / BK; ++t) {
        if (t + 1 < DIM / BK)
            OSTAGE(cur ^ 1, (t + 1) * BK);

        short8 af[4], bf[2];
        #pragma unroll
        for (int mt = 0; mt < 4; ++mt)
            af[mt] = *reinterpret_cast<const short8*>(
                &As[cur][(mt * 16 + l16) * 32 + quad * 8]);
        #pragma unroll
        for (int nt = 0; nt < 2; ++nt)
            bf[nt] = *reinterpret_cast<const short8*>(
                &Bs[cur][(wn * 32 + nt * 16 + l16) * 32 + quad * 8]);
        #pragma unroll
        for (int mt = 0; mt < 4; ++mt)
            #pragma unroll
            for (int nt = 0; nt < 2; ++nt)
                acc[mt][nt] = __builtin_amdgcn_mfma_f32_16x16x32_bf16(
                    af[mt], bf[nt], acc[mt][nt], 0, 0, 0);

        __syncthreads();
        cur ^= 1;
    }
#undef OSTAGE

    #pragma unroll
    for (int mt = 0; mt < 4; ++mt)
        #pragma unroll
        for (int nt = 0; nt < 2; ++nt) {
            const int n = n0 + wn * 32 + nt * 16 + l16;
            #pragma unroll
            for (int r = 0; r < 4; ++r) {
                const int m = m0 + mt * 16 + quad * 4 + r;
                C[(size_t)m * DIM + n] = acc[mt][nt][r];
            }
        }
}

// ---------------------------------------------------------------------------
// Causal flash attention, UNPAIRED-LPT (r13-verified): 1024 blocks, ONE
// 64-row tile each, heavy tiles first.  3 blocks/CU resident.  Monotone j
// staging pointers; diagonal mask only at s == total-1; epilogue hoisted.
// Double-Q per wave + K/V LDS dbuf, single barrier per step.
// O written in-place over Q (block-private rows).
// ---------------------------------------------------------------------------
__global__ __launch_bounds__(256) void attn_causal(
    __hip_bfloat16* __restrict__ qkv)
{
    __shared__ __align__(16) short kt[2][64 * 64];     // [slot][j][k], swizzled
    __shared__ __align__(16) short vt[2][64 * 64];     // [slot][dv][j], swizzled
    __shared__ __align__(16) short pt[2][2][16 * 72];  // [g][sub] P^T [q][j]

    const int id    = blockIdx.x;        // 0..1023
    const int combo = id & 31;           // (h,b): combo%8 pins XCD class
    const int b     = combo >> 4;
    const int h     = combo & 15;
    const int tile  = 31 - (id >> 5);    // LPT: heaviest (32 steps) first
    const int total = tile + 1;

    const size_t hoff = (size_t)(b * HEADS + h) * SEQ * DIMH;
    const size_t one  = (size_t)BATCH * SEQ * DIM;
    __hip_bfloat16* qb        = qkv + hoff;             // Q in, O out (in-place)
    const __hip_bfloat16* kb  = qkv + one + hoff;       // [n][dv]
    const __hip_bfloat16* vtg = qkv + 2 * one + hoff;   // [dv][n]

    const int tid  = threadIdx.x;
    const int wv   = tid >> 6;
    const int g    = wv >> 1;            // wave-pair (0,1)
    const int jh   = wv & 1;             // j-half owner
    const int lane = tid & 63;
    const int quad = lane >> 4;
    const int l16  = lane & 15;
    const int xr   = l16 & 7;

    const int crow = tid >> 3;           // staging row 0..31 (x2)
    const int cjc  = tid & 7;
    const int coff = ((cjc ^ (crow & 7)) * 8);

    const short8 kone8 = {0x3F80, 0x3F80, 0x3F80, 0x3F80,
                          0x3F80, 0x3F80, 0x3F80, 0x3F80};

    const int qbase = tile * 64 + g * 16;   // sub sb: rows qbase + sb*32 .. +15
    short8 aq[2][2];                     // [sub][half]
    #pragma unroll
    for (int sb = 0; sb < 2; ++sb) {
        aq[sb][0] = *reinterpret_cast<const short8*>(
            qb + (size_t)(qbase + sb * 32 + l16) * DIMH + quad * 8);
        aq[sb][1] = *reinterpret_cast<const short8*>(
            qb + (size_t)(qbase + sb * 32 + l16) * DIMH + 32 + quad * 8);
    }
    floatx4 oacc[2][4] = {};             // [sub][dt]
    floatx4 lsum[2] = {};

    // incrementing staging pointers (j advances 0,64,128,... monotonically)
    const __hip_bfloat16* kp0 = kb + (size_t)crow * DIMH + cjc * 8;
    const __hip_bfloat16* kp1 = kb + (size_t)(crow + 32) * DIMH + cjc * 8;
    const __hip_bfloat16* vp0 = vtg + (size_t)crow * SEQ + cjc * 8;
    const __hip_bfloat16* vp1 = vtg + (size_t)(crow + 32) * SEQ + cjc * 8;

    short8 kreg[2], vreg[2];
    kreg[0] = *reinterpret_cast<const short8*>(kp0);
    kreg[1] = *reinterpret_cast<const short8*>(kp1);
    vreg[0] = *reinterpret_cast<const short8*>(vp0);
    vreg[1] = *reinterpret_cast<const short8*>(vp1);
    kp0 += 64 * DIMH; kp1 += 64 * DIMH; vp0 += 64; vp1 += 64;

    *reinterpret_cast<short8*>(&kt[0][crow * 64 + coff])        = kreg[0];
    *reinterpret_cast<short8*>(&kt[0][(crow + 32) * 64 + coff]) = kreg[1];
    *reinterpret_cast<short8*>(&vt[0][crow * 64 + coff])        = vreg[0];
    *reinterpret_cast<short8*>(&vt[0][(crow + 32) * 64 + coff]) = vreg[1];
    __syncthreads();

    int cur = 0;
    for (int s = 0; s < total; ++s) {
        const int j0 = s * 64;
        const bool hasn = (s + 1 < total);

        if (hasn) {                      // issue next step's K/V loads early
            kreg[0] = *reinterpret_cast<const short8*>(kp0);
            kreg[1] = *reinterpret_cast<const short8*>(kp1);
            vreg[0] = *reinterpret_cast<const short8*>(vp0);
            vreg[1] = *reinterpret_cast<const short8*>(vp1);
            kp0 += 64 * DIMH; kp1 += 64 * DIMH; vp0 += 64; vp1 += 64;
        }

        // St[j][q] = K Q^T: read K fragments ONCE, use for both subs
        floatx4 st[2][2];                // [sub][tt]
        #pragma unroll
        for (int tt = 0; tt < 2; ++tt) {
            const int rw = (jh * 2 + tt) * 16 + l16;
            short8 a0 = *reinterpret_cast<const short8*>(&kt[cur][rw * 64 + (quad ^ xr) * 8]);
            short8 a1 = *reinterpret_cast<const short8*>(&kt[cur][rw * 64 + ((quad + 4) ^ xr) * 8]);
            #pragma unroll
            for (int sb = 0; sb < 2; ++sb) {
                floatx4 zz = {};
                zz         = __builtin_amdgcn_mfma_f32_16x16x32_bf16(a0, aq[sb][0], zz, 0, 0, 0);
                st[sb][tt] = __builtin_amdgcn_mfma_f32_16x16x32_bf16(a1, aq[sb][1], zz, 0, 0, 0);
            }
        }

        if (s == total - 1) {            // only the final step touches the diagonal
            #pragma unroll
            for (int sb = 0; sb < 2; ++sb) {
                const int qg = qbase + sb * 32 + l16;
                #pragma unroll
                for (int tt = 0; tt < 2; ++tt)
                    #pragma unroll
                    for (int r = 0; r < 4; ++r) {
                        const int jg = j0 + (jh * 2 + tt) * 16 + quad * 4 + r;
                        if (jg > qg) st[sb][tt][r] = -3.0e38f;
                    }
            }
        }

        #pragma unroll
        for (int sb = 0; sb < 2; ++sb)
            #pragma unroll
            for (int tt = 0; tt < 2; ++tt)
                #pragma unroll
                for (int r = 0; r < 4; ++r)
                    st[sb][tt][r] = __builtin_amdgcn_exp2f(st[sb][tt][r] - SM_SHIFT);

        // P^T pack per sub (wave-disjoint pt regions)
        short8 ph[2];
        #pragma unroll
        for (int sb = 0; sb < 2; ++sb) {
            #pragma unroll
            for (int tt = 0; tt < 2; ++tt) {
                const int t = jh * 2 + tt;
                *reinterpret_cast<unsigned*>(&pt[g][sb][l16 * 72 + t * 16 + quad * 4]) =
                    pk_trunc(st[sb][tt][0], st[sb][tt][1]);
                *reinterpret_cast<unsigned*>(&pt[g][sb][l16 * 72 + t * 16 + quad * 4 + 2]) =
                    pk_trunc(st[sb][tt][2], st[sb][tt][3]);
            }
            ph[sb] = *reinterpret_cast<const short8*>(&pt[g][sb][l16 * 72 + jh * 32 + quad * 8]);
            lsum[sb] = __builtin_amdgcn_mfma_f32_16x16x32_bf16(kone8, ph[sb], lsum[sb], 0, 0, 0);
        }

        // O^T += V^T P^T: read V fragment ONCE, use for both subs
        #pragma unroll
        for (int dt = 0; dt < 4; ++dt) {
            const int rw = dt * 16 + l16;
            short8 vh = *reinterpret_cast<const short8*>(
                &vt[cur][rw * 64 + ((quad + 4 * jh) ^ xr) * 8]);
            #pragma unroll
            for (int sb = 0; sb < 2; ++sb)
                oacc[sb][dt] = __builtin_amdgcn_mfma_f32_16x16x32_bf16(
                    vh, ph[sb], oacc[sb][dt], 0, 0, 0);
        }

        if (hasn) {                      // commit next step's K/V into other slot
            *reinterpret_cast<short8*>(&kt[cur ^ 1][crow * 64 + coff])        = kreg[0];
            *reinterpret_cast<short8*>(&kt[cur ^ 1][(crow + 32) * 64 + coff]) = kreg[1];
            *reinterpret_cast<short8*>(&vt[cur ^ 1][crow * 64 + coff])        = vreg[0];
            *reinterpret_cast<short8*>(&vt[cur ^ 1][(crow + 32) * 64 + coff]) = vreg[1];
        }

        __syncthreads();                 // commits visible; [cur] reads all done
        cur ^= 1;
    }

    // ---- epilogue (outside the loop; kt/vt dead, last barrier already done)
    float* xo = reinterpret_cast<float*>(g == 0 ? kt[0] : vt[0]);  // 2048 floats
    float* xl = reinterpret_cast<float*>(pt);                      // 256 floats
    if (jh == 1) {
        #pragma unroll
        for (int sb = 0; sb < 2; ++sb) {
            #pragma unroll
            for (int dt = 0; dt < 4; ++dt)
                #pragma unroll
                for (int r = 0; r < 4; ++r)
                    xo[sb * 1024 + (dt * 4 + r) * 64 + lane] = oacc[sb][dt][r];
            xl[(g * 2 + sb) * 64 + lane] = lsum[sb][0];
        }
    }
    __syncthreads();
    if (jh == 0) {
        #pragma unroll
        for (int sb = 0; sb < 2; ++sb) {
            const float rl = 1.0f / (lsum[sb][0] + xl[(g * 2 + sb) * 64 + lane]);
            #pragma unroll
            for (int dt = 0; dt < 4; ++dt)
                #pragma unroll
                for (int r = 0; r < 4; ++r) {
                    const float ov = oacc[sb][dt][r] +
                                     xo[sb * 1024 + (dt * 4 + r) * 64 + lane];
                    qb[(size_t)(qbase + sb * 32 + l16) * DIMH + dt * 16 + quad * 4 + r] =
                        __float2bfloat16(ov * rl);
                }
        }
    }
}

// ---------------------------------------------------------------------------

extern "C" void kernel_launch(void* const* d_in, const int* in_sizes, int n_in,
                              void* d_out, int out_size, void* d_ws, size_t ws_size,
                              hipStream_t stream) {
    const float* x  = (const float*)d_in[0];
    const float* Wq = (const float*)d_in[1];
    const float* Wk = (const float*)d_in[2];
    const float* Wv = (const float*)d_in[3];
    const float* Wo = (const float*)d_in[4];

    // ws: qkv bf16 [0,24M) | wobf bf16 [24M,26M)
    __hip_bfloat16* qkv  = (__hip_bfloat16*)d_ws;
    __hip_bfloat16* wobf = (__hip_bfloat16*)((char*)d_ws + (size_t)24 * 1024 * 1024);

    // d_out (16 MB) as bf16 scratch until gemm_out overwrites it
    __hip_bfloat16* xbf = (__hip_bfloat16*)d_out;
    __hip_bfloat16* wbf = xbf + (size_t)BATCH * SEQ * DIM;

    conv_all  <<<8192, 256, 0, stream>>>(x, Wq, Wk, Wv, Wo, xbf, wobf);
    gemm_qkv  <<<dim3((BATCH * SEQ) / 128, (3 * DIM) / 128), 256, 0, stream>>>(xbf, wbf, qkv);
    attn_causal<<<dim3(1024), 256, 0, stream>>>(qkv);
    gemm_out  <<<dim3((BATCH * SEQ) / 64, DIM / 128), 256, 0, stream>>>(qkv, wobf, (float*)d_out);
}